// Round 3
// baseline (2421.897 us; speedup 1.0000x reference)
//
#include <hip/hip_runtime.h>

#define NUM_V 100000
#define NUM_E 400000
#define NNZ   800000
#define D     128
#define FOURD 512
#define KTOT  256   // K = D (msg) + D (h_e)

typedef _Float16 half8  __attribute__((ext_vector_type(8)));
typedef _Float16 half4v __attribute__((ext_vector_type(4)));
typedef float    f32x4  __attribute__((ext_vector_type(4)));

__device__ __forceinline__ float sigmoidf_(float x) {
    return 1.f / (1.f + __expf(-x));
}
__device__ __forceinline__ float tanhf_(float x) {
    // 1 - 2/(e^{2x}+1); correct limits at +-inf
    return 1.f - 2.f / (__expf(2.f * x) + 1.f);
}

// COO SpMM scatter: msg[row] += val * x_v[col].  32 threads (half wave) per nnz, float4 each.
__global__ void spmm_kernel(const float4* __restrict__ xv4,
                            const float* __restrict__ edge_val,
                            const int* __restrict__ edge_row,
                            const int* __restrict__ edge_col,
                            float* msg) {
    int t  = blockIdx.x * 256 + threadIdx.x;
    int e  = t >> 5;
    int c4 = t & 31;
    int row = edge_row[e];
    int col = edge_col[e];
    float val = edge_val[e];
    float4 v = xv4[col * 32 + c4];
    float* dst = msg + (size_t)row * D + c4 * 4;
    atomicAdd(dst + 0, val * v.x);
    atomicAdd(dst + 1, val * v.y);
    atomicAdd(dst + 2, val * v.z);
    atomicAdd(dst + 3, val * v.w);
}

#define BM 64
#define LDA_H 264   // 256 + 8 halfs pad -> 528 B row stride (breaks the 512 B same-bank pattern)

// Fused GEMM (M=NUM_E, N=512, K=256, fp16 MFMA, fp32 accum) + LSTM gate math.
// 8 waves: wave w owns d-columns [16w,16w+16) across all 4 gates. All 64 rows per wave.
__global__ __launch_bounds__(512)
void gemm_lstm_kernel(const float* msg,                 // aliases out_c
                      const float* __restrict__ h_e,
                      const float* __restrict__ c_e,
                      const float* __restrict__ W_ih,
                      const float* __restrict__ W_hh,
                      const float* __restrict__ b_ih,
                      const float* __restrict__ b_hh,
                      float* __restrict__ out_h,
                      float* out_c) {
    __shared__ _Float16 Atile[BM * LDA_H];
    const int tid  = threadIdx.x;
    const int wid  = tid >> 6;     // 0..7
    const int lane = tid & 63;
    const int lo   = lane & 15;
    const int hi   = lane >> 4;    // 0..3
    const size_t r0 = (size_t)blockIdx.x * BM;

    // ---- stage A tile: k[0,128) = msg (fp32->fp16), k[128,256) = h_e ----
    {
        const int rr = tid >> 5;   // 0..15
        const int c4 = tid & 31;   // float4 index within 128 floats
#pragma unroll
        for (int p = 0; p < 4; ++p) {
            const int row = rr + p * 16;
            float4 v = *((const float4*)(msg + (r0 + row) * D) + c4);
            half4v hv;
            hv.x = (_Float16)v.x; hv.y = (_Float16)v.y;
            hv.z = (_Float16)v.z; hv.w = (_Float16)v.w;
            *(half4v*)(&Atile[row * LDA_H + c4 * 4]) = hv;
            float4 u = *((const float4*)(h_e + (r0 + row) * D) + c4);
            half4v hu;
            hu.x = (_Float16)u.x; hu.y = (_Float16)u.y;
            hu.z = (_Float16)u.z; hu.w = (_Float16)u.w;
            *(half4v*)(&Atile[row * LDA_H + D + c4 * 4]) = hu;
        }
    }
    __syncthreads();

    // ---- K-loop: 8 steps of K=32, 16 MFMAs/step.  B read from fp32 W (L2-resident). ----
    f32x4 acc[4][4] = {};   // [m-tile][gate]
    const int nbase = wid * 16 + lo;   // output column within a gate

#pragma unroll
    for (int kt = 0; kt < 8; ++kt) {
        // kt<4 -> W_ih columns k=kt*32.. ; kt>=4 -> W_hh columns k-128
        const float* wbase = (kt < 4) ? W_ih : W_hh;
        const int    koff  = (kt < 4) ? (kt * 32) : (kt * 32 - 128);
        half8 a[4], b[4];
#pragma unroll
        for (int m = 0; m < 4; ++m)
            a[m] = *(const half8*)(&Atile[(m * 16 + lo) * LDA_H + kt * 32 + hi * 8]);
#pragma unroll
        for (int g = 0; g < 4; ++g) {
            const float* wp = wbase + (size_t)(g * D + nbase) * D + koff + hi * 8;
            f32x4 w0 = *(const f32x4*)wp;
            f32x4 w1 = *(const f32x4*)(wp + 4);
            half8 bb;
            bb[0] = (_Float16)w0.x; bb[1] = (_Float16)w0.y;
            bb[2] = (_Float16)w0.z; bb[3] = (_Float16)w0.w;
            bb[4] = (_Float16)w1.x; bb[5] = (_Float16)w1.y;
            bb[6] = (_Float16)w1.z; bb[7] = (_Float16)w1.w;
            b[g] = bb;
        }
#pragma unroll
        for (int m = 0; m < 4; ++m)
#pragma unroll
            for (int g = 0; g < 4; ++g)
                acc[m][g] = __builtin_amdgcn_mfma_f32_16x16x32_f16(a[m], b[g], acc[m][g], 0, 0, 0);
    }

    // ---- epilogue: gates -> (h_new, c_new) ----
    const int d = nbase;
    const float bi = b_ih[d]         + b_hh[d];
    const float bf = b_ih[D + d]     + b_hh[D + d];
    const float bg = b_ih[2 * D + d] + b_hh[2 * D + d];
    const float bo = b_ih[3 * D + d] + b_hh[3 * D + d];
#pragma unroll
    for (int m = 0; m < 4; ++m) {
#pragma unroll
        for (int j = 0; j < 4; ++j) {
            const size_t row = r0 + m * 16 + hi * 4 + j;   // C/D: row=(lane>>4)*4+reg
            float iv = sigmoidf_(acc[m][0][j] + bi);
            float fv = sigmoidf_(acc[m][1][j] + bf);
            float gv = tanhf_  (acc[m][2][j] + bg);
            float ov = sigmoidf_(acc[m][3][j] + bo);
            float cold = c_e[row * D + d];
            float cn = fv * cold + iv * gv;
            float hn = ov * tanhf_(cn);
            out_h[row * D + d] = hn;
            out_c[row * D + d] = cn;   // overwrites msg (already staged to LDS pre-barrier)
        }
    }
}

extern "C" void kernel_launch(void* const* d_in, const int* in_sizes, int n_in,
                              void* d_out, int out_size, void* d_ws, size_t ws_size,
                              hipStream_t stream) {
    (void)in_sizes; (void)n_in; (void)out_size; (void)d_ws; (void)ws_size;
    const float* x_v      = (const float*)d_in[0];
    const float* h_e      = (const float*)d_in[1];
    const float* c_e      = (const float*)d_in[2];
    const float* edge_val = (const float*)d_in[3];
    const int*   edge_row = (const int*)d_in[4];
    const int*   edge_col = (const int*)d_in[5];
    const float* W_ih     = (const float*)d_in[6];
    const float* W_hh     = (const float*)d_in[7];
    const float* b_ih     = (const float*)d_in[8];
    const float* b_hh     = (const float*)d_in[9];

    float* out_h = (float*)d_out;
    float* out_c = out_h + (size_t)NUM_E * D;
    float* msg   = out_c;   // SpMM accumulator aliases the c_new output region

    hipMemsetAsync(msg, 0, (size_t)NUM_E * D * sizeof(float), stream);
    spmm_kernel<<<(NNZ * 32) / 256, 256, 0, stream>>>((const float4*)x_v, edge_val,
                                                      edge_row, edge_col, msg);
    gemm_lstm_kernel<<<NUM_E / BM, 512, 0, stream>>>(msg, h_e, c_e, W_ih, W_hh,
                                                     b_ih, b_hh, out_h, out_c);
}